// Round 10
// baseline (98.201 us; speedup 1.0000x reference)
//
#include <hip/hip_runtime.h>

static constexpr float DEG2RAD = 0.017453292519943295f;
static constexpr int B_N    = 8192;  // nodes per bucket -> 64KB LDS float2 hist
static constexpr int MAX_NS = 40;    // max edge-list splits (2 blocks/CU)
static constexpr int QCAP   = 4032;  // LDS message queue capacity (15.75 KB)
static constexpr int CHUNK  = 8192;  // edges scanned per block between drain checks

__device__ __forceinline__ int mbcnt64(unsigned long long m) {
    return __builtin_amdgcn_mbcnt_hi((unsigned)(m >> 32),
           __builtin_amdgcn_mbcnt_lo((unsigned)m, 0u));
}

__global__ void __launch_bounds__(256) node_ef_kernel(
    const float* __restrict__ x, const float* __restrict__ xymean,
    const float* __restrict__ xystd, float2* __restrict__ ef, int n)
{
    int i = blockIdx.x * 256 + threadIdx.x;
    if (i >= n) return;
    float vm = fmaf(x[i * 6 + 0], xystd[0], xymean[0]);
    float va = fmaf(x[i * 6 + 1], xystd[1], xymean[1]) * DEG2RAD;
    float s, c;
    sincosf(va, &s, &c);
    ef[i] = make_float2(vm * c, vm * s);
}

// Bucketed scan with stream compaction. Phase A: scan edges, ballot-compact
// hit messages (rec = (e<<1)|side) into LDS queue (1 wave-aggregated LDS
// atomic per wave). Drain: all lanes process real messages densely into the
// LDS histogram. SW: slice pinned to XCD so same-slice blocks share one L2.
template <bool SW>
__global__ void __launch_bounds__(1024, 8) scan_kernel(
    const int* __restrict__ src, const int* __restrict__ dst,
    const float2* __restrict__ eattr, const float2* __restrict__ ef,
    const float* __restrict__ edgemean, const float* __restrict__ edgestd,
    float2* __restrict__ partial, int ne, int nb, int slice)
{
    __shared__ float2 sAgg[B_N];
    __shared__ int q[QCAP];
    __shared__ int qn;
    int b, sp;
    if (SW) {
        int xp = blockIdx.x & 7, t = blockIdx.x >> 3;
        b  = t % nb;
        sp = (t / nb) * 8 + xp;
    } else {
        b  = blockIdx.x % nb;
        sp = blockIdx.x / nb;
    }
    const int base = b * B_N;
    for (int l = threadIdx.x; l < B_N; l += 1024) sAgg[l] = make_float2(0.f, 0.f);
    if (threadIdx.x == 0) qn = 0;
    __syncthreads();

    const int e0 = sp * slice;
    const int e1 = min(ne, e0 + slice);
    const float em0 = edgemean[0], em1 = edgemean[1];
    const float es0 = edgestd[0],  es1 = edgestd[1];
    const int lane = threadIdx.x & 63;

    // Process one message: hit node h (in bucket), other node o.
    // A = e_h*(e_o-e_h) + f_h*(f_o-f_h); B = f_h*e_o - e_h*f_o
    // P = g*A + b*B; Q = g*B - b*A   (covers both directions)
    auto doMsg = [&](int rec) {
        int e = rec >> 1;
        int side = rec & 1;
        int si = src[e], di = dst[e];
        int h = side ? di : si;
        int o = side ? si : di;
        float2 ea = eattr[e];
        float r  = fmaf(ea.x, es0, em0);
        float xr = fmaf(ea.y, es1, em1);
        float inv = 1.0f / fmaf(r, r, xr * xr);
        float g = r * inv, bb = -xr * inv;
        float2 efh = ef[h];
        float2 efo = ef[o];
        float A = fmaf(efh.x, efo.x - efh.x, efh.y * (efo.y - efh.y));
        float B = fmaf(efh.y, efo.x, -efh.x * efo.y);
        int l = h - base;
        atomicAdd(&sAgg[l].x, fmaf(g, A, bb * B));
        atomicAdd(&sAgg[l].y, fmaf(g, B, -bb * A));
    };

    // Wave-aggregated queue push for one edge (up to 2 messages).
    auto pushEdge = [&](int si, int di, int e, bool valid) {
        bool hs = valid && ((unsigned)(si - base) < (unsigned)B_N);
        bool hd = valid && ((unsigned)(di - base) < (unsigned)B_N);
        unsigned long long ms = __ballot(hs);
        unsigned long long md = __ballot(hd);
        int cs = __popcll(ms);
        int tot = cs + __popcll(md);
        if (tot == 0) return;            // wave-uniform
        int bq = 0;
        if (lane == 0) bq = atomicAdd(&qn, tot);
        bq = __shfl(bq, 0, 64);
        if (hs) {
            int idx = bq + mbcnt64(ms);
            if (idx < QCAP) q[idx] = e << 1; else doMsg(e << 1);
        }
        if (hd) {
            int idx = bq + cs + mbcnt64(md);
            if (idx < QCAP) q[idx] = (e << 1) | 1; else doMsg((e << 1) | 1);
        }
    };

    for (int c0 = e0; c0 < e1; c0 += CHUNK) {
        int p = c0 + 2 * (int)threadIdx.x;
        #pragma unroll
        for (int k = 0; k < CHUNK / 2048; ++k) {
            int e = p + k * 2048;
            bool v = e < e1;             // e,e1 even -> pair never straddles
            int2 ss = make_int2(-1, -1), dd = make_int2(-1, -1);
            if (v) {
                ss = *(const int2*)(src + e);
                dd = *(const int2*)(dst + e);
            }
            pushEdge(ss.x, dd.x, e, v);
            pushEdge(ss.y, dd.y, e + 1, v);
        }
        __syncthreads();
        bool last = (c0 + CHUNK) >= e1;
        int m = min(qn, QCAP);           // uniform post-barrier
        if (m >= QCAP / 2 || (last && m > 0)) {
            for (int i = threadIdx.x; i < m; i += 1024) doMsg(q[i]);
            __syncthreads();
            if (threadIdx.x == 0) qn = 0;
        }
        __syncthreads();
    }

    float2* outp = partial + ((size_t)sp * nb + b) * B_N;
    for (int l = threadIdx.x; l < B_N; l += 1024) outp[l] = sAgg[l];
}

// Fallback (tiny ws): plain device atomics (~320us, R5).
__global__ void __launch_bounds__(256) edge_atomic_kernel(
    const int* __restrict__ eidx, const float2* __restrict__ eattr,
    const float2* __restrict__ ef, const float* __restrict__ edgemean,
    const float* __restrict__ edgestd, float* __restrict__ agg, int ne)
{
    int e = blockIdx.x * 256 + threadIdx.x;
    if (e >= ne) return;
    int s = eidx[e];
    int d = eidx[ne + e];
    float2 ea = eattr[e];
    float r  = fmaf(ea.x, edgestd[0], edgemean[0]);
    float xr = fmaf(ea.y, edgestd[1], edgemean[1]);
    float inv = 1.0f / fmaf(r, r, xr * xr);
    float g = r * inv;
    float b = -xr * inv;
    float2 efi = ef[s];
    float2 efj = ef[d];
    float ei_ = efi.x, fi = efi.y, ej_ = efj.x, fj = efj.y;
    float A1 = fmaf(ei_, ej_ - ei_, fi * (fj - fi));
    float B1 = fmaf(fi, ej_, -ei_ * fj);
    float A2 = fmaf(ej_, ei_ - ej_, fj * (fi - fj));
    atomicAdd(&agg[2 * s],     fmaf(g, A1, b * B1));
    atomicAdd(&agg[2 * s + 1], fmaf(g, B1, -b * A1));
    atomicAdd(&agg[2 * d],     fmaf(g, A2, -b * B1));
    atomicAdd(&agg[2 * d + 1], fmaf(-g, B1, -b * A2));
}

// Fold ns partials per node + fused MSE -> single scalar.
// ns==0: partial is a dense float2[n] (atomic fallback).
__global__ void __launch_bounds__(256) reduce_kernel(
    const float* __restrict__ x, const float* __restrict__ y,
    const float* __restrict__ xymean, const float* __restrict__ xystd,
    const float2* __restrict__ partial, float* __restrict__ out,
    int n, int nb, int ns)
{
    int i = blockIdx.x * 256 + threadIdx.x;
    float v = 0.0f;
    if (i < n) {
        float P = 0.0f, Q = 0.0f;
        if (ns > 0) {
            int b = i / B_N;
            int l = i & (B_N - 1);
            const float2* p = partial + (size_t)b * B_N + l;
            for (int s = 0; s < ns; ++s) {
                float2 a = p[(size_t)s * nb * B_N];
                P += a.x;
                Q += a.y;
            }
        } else {
            float2 a = partial[i];
            P = a.x;
            Q = a.y;
        }
        float xd2 = fmaf(x[i * 6 + 2], xystd[2], xymean[2]);
        float xd3 = fmaf(x[i * 6 + 3], xystd[3], xymean[3]);
        float dP = xd2 - P;
        float dQ = xd3 - Q;
        float dpq = fmaf(dP, dP, dQ * dQ);
        float msep = 0.0f;
        #pragma unroll
        for (int c = 0; c < 6; ++c) {
            float dxy = x[i * 6 + c] - y[i * 6 + c];
            msep = fmaf(dxy, dxy, msep);
        }
        // out = 0.5*mse_sum/(6N) + 0.01*dpq_sum/N
        v = dpq * (0.01f / (float)n) + msep * (0.5f / (6.0f * (float)n));
    }
    #pragma unroll
    for (int off = 32; off; off >>= 1) v += __shfl_down(v, off, 64);
    __shared__ float ls_[4];
    int lane = threadIdx.x & 63, wv = threadIdx.x >> 6;
    if (lane == 0) ls_[wv] = v;
    __syncthreads();
    if (threadIdx.x == 0) atomicAdd(out, ls_[0] + ls_[1] + ls_[2] + ls_[3]);
}

extern "C" void kernel_launch(void* const* d_in, const int* in_sizes, int n_in,
                              void* d_out, int out_size, void* d_ws, size_t ws_size,
                              hipStream_t stream) {
    const float* x        = (const float*)d_in[0];
    const int*   eidx     = (const int*)d_in[1];
    const float* eattr    = (const float*)d_in[2];
    const float* y        = (const float*)d_in[3];
    const float* xymean   = (const float*)d_in[4];
    const float* xystd    = (const float*)d_in[5];
    const float* edgemean = (const float*)d_in[6];
    const float* edgestd  = (const float*)d_in[7];
    float* out = (float*)d_out;

    const int n  = in_sizes[0] / 6;   // 100000 nodes
    const int ne = in_sizes[2] / 2;   // 1600000 edges

    const int nb = (n + B_N - 1) / B_N;                         // 13 buckets
    const size_t ef_bytes  = (size_t)n * sizeof(float2);        // 0.8 MB
    const size_t per_split = (size_t)nb * B_N * sizeof(float2); // 0.85 MB

    int ns = 0;
    if (ws_size > ef_bytes) {
        size_t fit = (ws_size - ef_bytes) / per_split;
        ns = (fit > (size_t)MAX_NS) ? MAX_NS : (int)fit;
    }
    bool sw = false;
    if (ns >= 8) { ns &= ~7; sw = true; }   // multiple of 8 -> bijective swizzle

    (void)hipMemsetAsync(out, 0, sizeof(float), stream);

    if (ns >= 1) {
        float2* partial = (float2*)d_ws;
        float2* ef = (float2*)((char*)d_ws + per_split * ns);
        node_ef_kernel<<<(n + 255) / 256, 256, 0, stream>>>(x, xymean, xystd, ef, n);
        int slice = ((ne + ns - 1) / ns + 1) & ~1;   // even slice; ne even
        if (sw) {
            scan_kernel<true><<<nb * ns, 1024, 0, stream>>>(
                eidx, eidx + ne, (const float2*)eattr, ef, edgemean, edgestd,
                partial, ne, nb, slice);
        } else {
            scan_kernel<false><<<nb * ns, 1024, 0, stream>>>(
                eidx, eidx + ne, (const float2*)eattr, ef, edgemean, edgestd,
                partial, ne, nb, slice);
        }
        reduce_kernel<<<(n + 255) / 256, 256, 0, stream>>>(
            x, y, xymean, xystd, partial, out, n, nb, ns);
    } else {
        float2* agg = (float2*)d_ws;
        float2* ef = (float2*)((char*)d_ws + (size_t)n * sizeof(float2));
        (void)hipMemsetAsync(agg, 0, (size_t)n * sizeof(float2), stream);
        node_ef_kernel<<<(n + 255) / 256, 256, 0, stream>>>(x, xymean, xystd, ef, n);
        edge_atomic_kernel<<<(ne + 255) / 256, 256, 0, stream>>>(
            eidx, (const float2*)eattr, ef, edgemean, edgestd, (float*)agg, ne);
        reduce_kernel<<<(n + 255) / 256, 256, 0, stream>>>(
            x, y, xymean, xystd, agg, out, n, nb, 0);
    }
}

// Round 11
// 79.380 us; speedup vs baseline: 1.2371x; 1.2371x over previous
//
#include <hip/hip_runtime.h>

static constexpr float DEG2RAD = 0.017453292519943295f;
static constexpr int B_N    = 16384; // nodes per bucket -> 128KB LDS float2 hist
static constexpr int MAX_NS = 32;    // edge-list splits (grid = 7*32 = 224 blocks)

__global__ void __launch_bounds__(256) node_ef_kernel(
    const float* __restrict__ x, const float* __restrict__ xymean,
    const float* __restrict__ xystd, float2* __restrict__ ef, int n)
{
    int i = blockIdx.x * 256 + threadIdx.x;
    if (i >= n) return;
    float vm = fmaf(x[i * 6 + 0], xystd[0], xymean[0]);
    float va = fmaf(x[i * 6 + 1], xystd[1], xymean[1]) * DEG2RAD;
    float s, c;
    sincosf(va, &s, &c);
    ef[i] = make_float2(vm * c, vm * s);
}

// Bucketed filtered scan (R9 structure, bigger bucket). Block (slice sp,
// bucket b) scans its edge slice with int4 loads (4 edges/thread/iter),
// accumulates messages for nodes in [b*B_N, b*B_N+B_N) via LDS atomics,
// then streams the 128KB histogram to its private partial region.
// SW: slice pinned to XCD (sp%8 == hw blockIdx%8) so the 7 same-slice
// blocks share one L2 -> each slice fetched beyond-L2 once.
template <bool SW>
__global__ void __launch_bounds__(1024) scan_kernel(
    const int* __restrict__ src, const int* __restrict__ dst,
    const float2* __restrict__ eattr, const float2* __restrict__ ef,
    const float* __restrict__ edgemean, const float* __restrict__ edgestd,
    float2* __restrict__ partial, int ne, int nb, int slice)
{
    __shared__ float2 sAgg[B_N];   // 128 KB
    int b, sp;
    if (SW) {
        int xp = blockIdx.x & 7, t = blockIdx.x >> 3;
        b  = t % nb;
        sp = (t / nb) * 8 + xp;
    } else {
        b  = blockIdx.x % nb;
        sp = blockIdx.x / nb;
    }
    const int base = b * B_N;
    for (int l = threadIdx.x; l < B_N; l += 1024) sAgg[l] = make_float2(0.f, 0.f);
    __syncthreads();
    const int e0 = sp * slice;
    const int e1 = min(ne, e0 + slice);
    const float em0 = edgemean[0], em1 = edgemean[1];
    const float es0 = edgestd[0],  es1 = edgestd[1];

    auto process = [&](int si, int di, int e) {
        unsigned ls = (unsigned)(si - base);
        unsigned ld = (unsigned)(di - base);
        bool hs = ls < (unsigned)B_N;
        bool hd = ld < (unsigned)B_N;
        if (!(hs || hd)) return;
        float2 ea = eattr[e];
        float r  = fmaf(ea.x, es0, em0);
        float xr = fmaf(ea.y, es1, em1);
        float inv = 1.0f / fmaf(r, r, xr * xr);
        float g  = r * inv;
        float bb = -xr * inv;
        float2 efi = ef[si];
        float2 efj = ef[di];
        float ei_ = efi.x, fi = efi.y, ej_ = efj.x, fj = efj.y;
        // A = e_i*e_j - e_i^2 + f_i*f_j - f_i^2 ; B = f_i*e_j - e_i*f_j
        float A1 = fmaf(ei_, ej_ - ei_, fi * (fj - fi));
        float B1 = fmaf(fi, ej_, -ei_ * fj);
        if (hs) {
            atomicAdd(&sAgg[ls].x, fmaf(g, A1, bb * B1));   // P into src
            atomicAdd(&sAgg[ls].y, fmaf(g, B1, -bb * A1));  // Q into src
        }
        if (hd) {
            float A2 = fmaf(ej_, ei_ - ej_, fj * (fi - fj));
            atomicAdd(&sAgg[ld].x, fmaf(g, A2, -bb * B1));  // P into dst (B2=-B1)
            atomicAdd(&sAgg[ld].y, fmaf(-g, B1, -bb * A2)); // Q into dst
        }
    };

    // slice, ne multiples of 4 -> int4 groups never straddle e1.
    for (int e = e0 + 4 * (int)threadIdx.x; e < e1; e += 4096) {
        int4 ss = *(const int4*)(src + e);
        int4 dd = *(const int4*)(dst + e);
        process(ss.x, dd.x, e);
        process(ss.y, dd.y, e + 1);
        process(ss.z, dd.z, e + 2);
        process(ss.w, dd.w, e + 3);
    }
    __syncthreads();
    float2* outp = partial + ((size_t)sp * nb + b) * B_N;
    for (int l = threadIdx.x; l < B_N; l += 1024) outp[l] = sAgg[l];
}

// Fallback (tiny ws): plain device atomics (~320us, R5).
__global__ void __launch_bounds__(256) edge_atomic_kernel(
    const int* __restrict__ eidx, const float2* __restrict__ eattr,
    const float2* __restrict__ ef, const float* __restrict__ edgemean,
    const float* __restrict__ edgestd, float* __restrict__ agg, int ne)
{
    int e = blockIdx.x * 256 + threadIdx.x;
    if (e >= ne) return;
    int s = eidx[e];
    int d = eidx[ne + e];
    float2 ea = eattr[e];
    float r  = fmaf(ea.x, edgestd[0], edgemean[0]);
    float xr = fmaf(ea.y, edgestd[1], edgemean[1]);
    float inv = 1.0f / fmaf(r, r, xr * xr);
    float g = r * inv;
    float b = -xr * inv;
    float2 efi = ef[s];
    float2 efj = ef[d];
    float ei_ = efi.x, fi = efi.y, ej_ = efj.x, fj = efj.y;
    float A1 = fmaf(ei_, ej_ - ei_, fi * (fj - fi));
    float B1 = fmaf(fi, ej_, -ei_ * fj);
    float A2 = fmaf(ej_, ei_ - ej_, fj * (fi - fj));
    atomicAdd(&agg[2 * s],     fmaf(g, A1, b * B1));
    atomicAdd(&agg[2 * s + 1], fmaf(g, B1, -b * A1));
    atomicAdd(&agg[2 * d],     fmaf(g, A2, -b * B1));
    atomicAdd(&agg[2 * d + 1], fmaf(-g, B1, -b * A2));
}

// Fold ns partials per node + fused MSE -> single scalar.
// ns==0: partial is a dense float2[n] (atomic fallback).
__global__ void __launch_bounds__(256) reduce_kernel(
    const float* __restrict__ x, const float* __restrict__ y,
    const float* __restrict__ xymean, const float* __restrict__ xystd,
    const float2* __restrict__ partial, float* __restrict__ out,
    int n, int nb, int ns)
{
    int i = blockIdx.x * 256 + threadIdx.x;
    float v = 0.0f;
    if (i < n) {
        float P = 0.0f, Q = 0.0f;
        if (ns > 0) {
            int b = i / B_N;
            int l = i & (B_N - 1);
            const float2* p = partial + (size_t)b * B_N + l;
            for (int s = 0; s < ns; ++s) {
                float2 a = p[(size_t)s * nb * B_N];
                P += a.x;
                Q += a.y;
            }
        } else {
            float2 a = partial[i];
            P = a.x;
            Q = a.y;
        }
        float xd2 = fmaf(x[i * 6 + 2], xystd[2], xymean[2]);
        float xd3 = fmaf(x[i * 6 + 3], xystd[3], xymean[3]);
        float dP = xd2 - P;
        float dQ = xd3 - Q;
        float dpq = fmaf(dP, dP, dQ * dQ);
        float msep = 0.0f;
        #pragma unroll
        for (int c = 0; c < 6; ++c) {
            float dxy = x[i * 6 + c] - y[i * 6 + c];
            msep = fmaf(dxy, dxy, msep);
        }
        // out = 0.5*mse_sum/(6N) + 0.01*dpq_sum/N
        v = dpq * (0.01f / (float)n) + msep * (0.5f / (6.0f * (float)n));
    }
    #pragma unroll
    for (int off = 32; off; off >>= 1) v += __shfl_down(v, off, 64);
    __shared__ float ls_[4];
    int lane = threadIdx.x & 63, wv = threadIdx.x >> 6;
    if (lane == 0) ls_[wv] = v;
    __syncthreads();
    if (threadIdx.x == 0) atomicAdd(out, ls_[0] + ls_[1] + ls_[2] + ls_[3]);
}

extern "C" void kernel_launch(void* const* d_in, const int* in_sizes, int n_in,
                              void* d_out, int out_size, void* d_ws, size_t ws_size,
                              hipStream_t stream) {
    const float* x        = (const float*)d_in[0];
    const int*   eidx     = (const int*)d_in[1];
    const float* eattr    = (const float*)d_in[2];
    const float* y        = (const float*)d_in[3];
    const float* xymean   = (const float*)d_in[4];
    const float* xystd    = (const float*)d_in[5];
    const float* edgemean = (const float*)d_in[6];
    const float* edgestd  = (const float*)d_in[7];
    float* out = (float*)d_out;

    const int n  = in_sizes[0] / 6;   // 100000 nodes
    const int ne = in_sizes[2] / 2;   // 1600000 edges

    const int nb = (n + B_N - 1) / B_N;                         // 7 buckets
    const size_t ef_bytes  = (size_t)n * sizeof(float2);        // 0.8 MB
    const size_t per_split = (size_t)nb * B_N * sizeof(float2); // 0.92 MB

    int ns = 0;
    if (ws_size > ef_bytes) {
        size_t fit = (ws_size - ef_bytes) / per_split;
        ns = (fit > (size_t)MAX_NS) ? MAX_NS : (int)fit;
    }
    bool sw = false;
    if (ns >= 8) { ns &= ~7; sw = true; }   // multiple of 8 -> bijective swizzle

    (void)hipMemsetAsync(out, 0, sizeof(float), stream);

    if (ns >= 1) {
        float2* partial = (float2*)d_ws;
        float2* ef = (float2*)((char*)d_ws + per_split * ns);
        node_ef_kernel<<<(n + 255) / 256, 256, 0, stream>>>(x, xymean, xystd, ef, n);
        int slice = ((ne + ns - 1) / ns + 3) & ~3;   // multiple of 4; ne%4==0
        if (sw) {
            scan_kernel<true><<<nb * ns, 1024, 0, stream>>>(
                eidx, eidx + ne, (const float2*)eattr, ef, edgemean, edgestd,
                partial, ne, nb, slice);
        } else {
            scan_kernel<false><<<nb * ns, 1024, 0, stream>>>(
                eidx, eidx + ne, (const float2*)eattr, ef, edgemean, edgestd,
                partial, ne, nb, slice);
        }
        reduce_kernel<<<(n + 255) / 256, 256, 0, stream>>>(
            x, y, xymean, xystd, partial, out, n, nb, ns);
    } else {
        float2* agg = (float2*)d_ws;
        float2* ef = (float2*)((char*)d_ws + (size_t)n * sizeof(float2));
        (void)hipMemsetAsync(agg, 0, (size_t)n * sizeof(float2), stream);
        node_ef_kernel<<<(n + 255) / 256, 256, 0, stream>>>(x, xymean, xystd, ef, n);
        edge_atomic_kernel<<<(ne + 255) / 256, 256, 0, stream>>>(
            eidx, (const float2*)eattr, ef, edgemean, edgestd, (float*)agg, ne);
        reduce_kernel<<<(n + 255) / 256, 256, 0, stream>>>(
            x, y, xymean, xystd, agg, out, n, nb, 0);
    }
}